// Round 9
// baseline (118.784 us; speedup 1.0000x reference)
//
#include <hip/hip_runtime.h>

#define NROWS 65536
#define DIM   64
#define NE    512

// d_out is FLOAT32: [ z_q (4194304) | indices-as-float (65536) | loss (1) ]
// Scratch (inside z_q region; consumed by vq_pick, then overwritten by
// vq_write_loss which is stream-ordered after it):
//   bytes [0,131072)       : preSplit — 512 rows x 256B: (-2e)_hi XOR-swizzled
//                            in [0,128), (-2e)_lo mirrored at +128
//   bytes [131072,139264)  : preY     — 512 x 16B: (ynorm_hi, ynorm_lo, 0...)
//   floats [34816,35328)   : ynorm f32 (np-pairwise, exact)
//   floats [1048576,+16384): cand u32 per row: win | runner<<9 | flag<<18
#define PREY_BYTES 131072
#define YN_FLT     34816
#define CAND_FLT   1048576

typedef __attribute__((ext_vector_type(8)))  short bf16x8;
typedef __attribute__((ext_vector_type(16))) float f32x16;

static __device__ __forceinline__ unsigned short bf16rne(float x) {
    unsigned int u = __float_as_uint(x);
    u += 0x7FFFu + ((u >> 16) & 1u);            // RNE (finite inputs only)
    return (unsigned short)(u >> 16);
}
static __device__ __forceinline__ float bf16tof(unsigned short h) {
    return __uint_as_float(((unsigned int)h) << 16);
}

// K0: one-time codebook prep (512 rows, 2 blocks).
__global__ __launch_bounds__(256) void vq_prep(
    const float* __restrict__ ew, float* out)
{
    const int r = blockIdx.x * 256 + threadIdx.x;     // 0..511
    float a[64];
    const float4* src = (const float4*)(ew + (size_t)r * DIM);
    #pragma unroll
    for (int q = 0; q < 16; ++q) {
        float4 v = src[q];
        a[q*4+0]=v.x; a[q*4+1]=v.y; a[q*4+2]=v.z; a[q*4+3]=v.w;
    }
    // numpy-pairwise ||e||^2 (exact np f32 order)
    float rc[8];
    #pragma unroll
    for (int j = 0; j < 8; ++j) rc[j] = __fmul_rn(a[j], a[j]);
    #pragma unroll
    for (int i = 8; i < 64; i += 8)
        #pragma unroll
        for (int j = 0; j < 8; ++j)
            rc[j] = __fadd_rn(rc[j], __fmul_rn(a[i+j], a[i+j]));
    float Y = __fadd_rn(__fadd_rn(__fadd_rn(rc[0],rc[1]),__fadd_rn(rc[2],rc[3])),
                        __fadd_rn(__fadd_rn(rc[4],rc[5]),__fadd_rn(rc[6],rc[7])));
    out[YN_FLT + r] = Y;
    unsigned short ynh = bf16rne(Y);
    unsigned short ynl = bf16rne(Y - bf16tof(ynh));
    bf16x8 py = {};
    py[0] = (short)ynh; py[1] = (short)ynl;
    *(bf16x8*)((char*)out + PREY_BYTES + r*16) = py;
    const int sw = (r & 7) << 4;
    char* base = (char*)out + (size_t)r * 256;
    #pragma unroll
    for (int c = 0; c < 8; ++c) {
        bf16x8 h, l;
        #pragma unroll
        for (int j = 0; j < 8; ++j) {
            float x = -2.0f * a[c*8+j];
            unsigned short hb = bf16rne(x);
            h[j] = (short)hb;
            l[j] = (short)bf16rne(x - bf16tof(hb));
        }
        int off = (c*16) ^ sw;
        *(bf16x8*)(base + off) = h;
        *(bf16x8*)(base + off + 128) = l;
    }
}

// K1: MFMA ranking (proven core). Emits win|runner|flag per row; winner first.
__global__ __launch_bounds__(256) void vq_mfma(
    const float* __restrict__ z, const float* pre, unsigned int* cand)
{
    __shared__ __align__(16) char lds[65536 + 8192];
    const int tid  = threadIdx.x;
    const int lane = tid & 63;
    const int w    = tid >> 6;
    const int hh   = lane >> 5;
    const int l31  = lane & 31;
    const int zrow = blockIdx.x * 128 + w * 32 + l31;

    bf16x8 zh[4], zl[4];
    {
        const float* zp = z + (size_t)zrow * DIM + hh * 8;
        #pragma unroll
        for (int kt = 0; kt < 4; ++kt) {
            float4 p0 = *(const float4*)(zp + kt*16);
            float4 p1 = *(const float4*)(zp + kt*16 + 4);
            float a[8] = {p0.x,p0.y,p0.z,p0.w,p1.x,p1.y,p1.z,p1.w};
            bf16x8 hv, lv;
            #pragma unroll
            for (int j = 0; j < 8; ++j) {
                unsigned short hb = bf16rne(a[j]);
                hv[j] = (short)hb;
                lv[j] = (short)bf16rne(a[j] - bf16tof(hb));
            }
            zh[kt] = hv; zl[kt] = lv;
        }
    }

    #pragma unroll
    for (int i = 0; i < 2; ++i)
        *(float4*)(lds + 65536 + (tid + 256*i)*16) =
            *(const float4*)((const char*)pre + PREY_BYTES + (tid + 256*i)*16);

    const bf16x8 zero8 = {};
    bf16x8 bones = {};
    if (hh == 0) { bones[0] = (short)0x3F80; bones[1] = (short)0x3F80; }

    float d1 = 3.4e38f, d2 = 3.4e38f;
    int   i1 = 0;

    for (int h = 0; h < 2; ++h) {
        __syncthreads();
        #pragma unroll
        for (int i = 0; i < 16; ++i)
            *(float4*)(lds + tid*16 + i*4096) =
                *(const float4*)((const char*)pre + h*65536 + tid*16 + i*4096);
        __syncthreads();

        for (int t = 0; t < 8; ++t) {
            const int   arow  = t*32 + l31;
            const char* abase = lds + arow*256;
            const int   sw    = (arow & 7) << 4;
            f32x16 acc;
            #pragma unroll
            for (int g = 0; g < 16; ++g) acc[g] = 0.f;
            #pragma unroll
            for (int kt = 0; kt < 4; ++kt) {
                const int kb = (kt*32 + hh*16) ^ sw;
                bf16x8 ah = *(const bf16x8*)(abase + kb);
                bf16x8 al = *(const bf16x8*)(abase + kb + 128);
                acc = __builtin_amdgcn_mfma_f32_32x32x16_bf16(ah, zh[kt], acc, 0,0,0);
                acc = __builtin_amdgcn_mfma_f32_32x32x16_bf16(ah, zl[kt], acc, 0,0,0);
                acc = __builtin_amdgcn_mfma_f32_32x32x16_bf16(al, zh[kt], acc, 0,0,0);
            }
            bf16x8 ay = *(const bf16x8*)(lds + 65536 + (h*256 + t*32 + l31)*16);
            if (hh) ay = zero8;
            acc = __builtin_amdgcn_mfma_f32_32x32x16_bf16(ay, bones, acc, 0,0,0);

            const int ebase = h*256 + t*32 + 4*hh;
            #pragma unroll
            for (int g = 0; g < 16; ++g) {
                float d = acc[g];
                int   e = ebase + (g & 3) + 8*(g >> 2);
                d2 = fminf(fmaxf(d, d1), d2);
                bool bt = d < d1;
                i1 = bt ? e : i1;
                d1 = fminf(d, d1);
            }
        }
    }

    // merge half-lane pools; winner ordered first; near-tie flag
    float od1 = __shfl_xor(d1, 32, 64);
    int   oi1 = __shfl_xor(i1, 32, 64);
    float od2 = __shfl_xor(d2, 32, 64);
    bool  oth = (od1 < d1) || (od1 == d1 && oi1 < i1);
    int   wi  = oth ? oi1 : i1;
    int   ri  = oth ? i1  : oi1;
    float s1  = fminf(d1, od1);
    float s2  = fminf(fmaxf(d1, od1), fminf(d2, od2));
    bool  flag = s2 < s1 + 5e-5f;
    if (hh == 0) {
        unsigned int pk = ((unsigned)wi & 511u) | (((unsigned)ri & 511u) << 9)
                        | (flag ? (1u << 18) : 0u);
        cand[zrow] = pk;
    }
}

// K2: unpack winners -> f32 indices; wave-parallel exact np rescan for the
// ~1% flagged rows. No z traffic for unflagged rows.
__global__ __launch_bounds__(256) void vq_pick(
    const float* __restrict__ z, const float* __restrict__ ew,
    const float* scratch, float* out)
{
    __shared__ float yn[NE];
    const int tid  = threadIdx.x;
    const int lane = tid & 63;
    const int w    = tid >> 6;

    #pragma unroll
    for (int i = 0; i < 2; ++i) yn[tid + 256*i] = scratch[YN_FLT + tid + 256*i];
    __syncthreads();

    const uint4* candp = (const uint4*)(scratch + CAND_FLT);
    uint4 pk4 = candp[blockIdx.x * 256 + tid];
    unsigned pks[4] = { pk4.x, pk4.y, pk4.z, pk4.w };
    int win[4];
    unsigned fm = 0;
    #pragma unroll
    for (int j = 0; j < 4; ++j) {
        win[j] = pks[j] & 511u;
        fm |= ((pks[j] >> 18) & 1u) << j;
    }

    unsigned long long any = __ballot(fm != 0);
    while (any) {
        int fl = __ffsll(any) - 1;
        any &= any - 1;
        unsigned fmf = (unsigned)__shfl((int)fm, fl, 64);
        #pragma unroll
        for (int j = 0; j < 4; ++j) {
            if ((fmf >> j) & 1u) {
                const int row = (blockIdx.x*256 + w*64 + fl)*4 + j;
                // all lanes load the row (broadcast), compute np-exact ||z||^2
                float zr[64];
                const float4* zsrc = (const float4*)(z + (size_t)row * DIM);
                #pragma unroll
                for (int q = 0; q < 16; ++q) {
                    float4 v = zsrc[q];
                    zr[q*4+0]=v.x; zr[q*4+1]=v.y; zr[q*4+2]=v.z; zr[q*4+3]=v.w;
                }
                float rc[8];
                #pragma unroll
                for (int jj = 0; jj < 8; ++jj) rc[jj] = __fmul_rn(zr[jj], zr[jj]);
                #pragma unroll
                for (int i = 8; i < 64; i += 8)
                    #pragma unroll
                    for (int jj = 0; jj < 8; ++jj)
                        rc[jj] = __fadd_rn(rc[jj], __fmul_rn(zr[i+jj], zr[i+jj]));
                float xn = __fadd_rn(__fadd_rn(__fadd_rn(rc[0],rc[1]),__fadd_rn(rc[2],rc[3])),
                                     __fadd_rn(__fadd_rn(rc[4],rc[5]),__fadd_rn(rc[6],rc[7])));
                // 8 embeds per lane: d = fl32(fl32(X+Y) - 2*f64dot)
                float bd = 3.4e38f; int bi = NE;
                for (int k = 0; k < 8; ++k) {
                    int e = lane + 64*k;
                    const float* ep = ew + (size_t)e * DIM;
                    double m = 0.0;
                    #pragma unroll
                    for (int q = 0; q < 16; ++q) {
                        float4 ev = *(const float4*)(ep + q*4);
                        m = fma((double)zr[q*4+0], (double)ev.x, m);
                        m = fma((double)zr[q*4+1], (double)ev.y, m);
                        m = fma((double)zr[q*4+2], (double)ev.z, m);
                        m = fma((double)zr[q*4+3], (double)ev.w, m);
                    }
                    float W = __fadd_rn(xn, yn[e]);
                    float d = __fadd_rn(W, -(2.0f * (float)m));
                    if (d < bd || (d == bd && e < bi)) { bd = d; bi = e; }
                }
                #pragma unroll
                for (int off = 32; off >= 1; off >>= 1) {
                    float od = __shfl_xor(bd, off, 64);
                    int   oi = __shfl_xor(bi, off, 64);
                    if (od < bd || (od == bd && oi < bi)) { bd = od; bi = oi; }
                }
                if (lane == fl) win[j] = bi;
            }
        }
    }

    float4 o;
    o.x = (float)win[0]; o.y = (float)win[1];
    o.z = (float)win[2]; o.w = (float)win[3];
    ((float4*)(out + (size_t)NROWS * DIM))[blockIdx.x * 256 + tid] = o;
}

// K3: gather e_win, write z_q (coalesced), AND accumulate f32 loss partials
// from a coalesced z read. Overwrites all scratch in the z_q region.
__global__ __launch_bounds__(256) void vq_write_loss(
    const float* __restrict__ z, const float* __restrict__ ew,
    float* out, float* __restrict__ part)
{
    __shared__ int ridx[64];
    __shared__ float wsum[4];
    const int tid = threadIdx.x;
    const int R0  = blockIdx.x * 64;
    if (tid < 64)
        ridx[tid] = ((int)out[(size_t)NROWS * DIM + R0 + tid]) & (NE - 1);
    __syncthreads();
    float s = 0.f;
    #pragma unroll
    for (int i = 0; i < 4; ++i) {
        int f4  = tid + 256 * i;
        int row = f4 >> 4;
        int c4  = f4 & 15;
        float4 v  = *(const float4*)(ew + (size_t)ridx[row] * DIM + c4 * 4);
        float4 zz = *(const float4*)(z + (size_t)R0 * DIM + (size_t)f4 * 4);
        *(float4*)(out + (size_t)R0 * DIM + (size_t)f4 * 4) = v;
        float dx = zz.x - v.x, dy = zz.y - v.y, dz2 = zz.z - v.z, dw = zz.w - v.w;
        s = fmaf(dx, dx, s); s = fmaf(dy, dy, s);
        s = fmaf(dz2, dz2, s); s = fmaf(dw, dw, s);
    }
    #pragma unroll
    for (int off = 32; off >= 1; off >>= 1) s += __shfl_xor(s, off, 64);
    if ((tid & 63) == 0) wsum[tid >> 6] = s;
    __syncthreads();
    if (tid == 0) part[blockIdx.x] = wsum[0]+wsum[1]+wsum[2]+wsum[3];
}

// K4: f64 sum of 1024 per-block partials -> loss slot.
__global__ __launch_bounds__(256) void vq_loss(
    const float* __restrict__ part, float* out)
{
    __shared__ double ws[4];
    int tid = threadIdx.x;
    double s = 0.0;
    #pragma unroll
    for (int i = 0; i < 4; ++i) s += (double)part[tid + 256*i];
    #pragma unroll
    for (int off = 32; off >= 1; off >>= 1) s += __shfl_xor(s, off, 64);
    if ((tid & 63) == 0) ws[tid >> 6] = s;
    __syncthreads();
    if (tid == 0)
        out[(size_t)NROWS*DIM + NROWS] =
            (float)(0.25 * (ws[0]+ws[1]+ws[2]+ws[3]) / (double)((size_t)NROWS*DIM));
}

extern "C" void kernel_launch(void* const* d_in, const int* in_sizes, int n_in,
                              void* d_out, int out_size, void* d_ws, size_t ws_size,
                              hipStream_t stream) {
    const float* z  = (const float*)d_in[0];
    const float* ew = (const float*)d_in[1];
    float* out  = (float*)d_out;
    float* part = (float*)d_ws;   // 1024 floats, fully overwritten every call
    vq_prep      <<<2,    256, 0, stream>>>(ew, out);
    vq_mfma      <<<512,  256, 0, stream>>>(z, out, (unsigned int*)(out + CAND_FLT));
    vq_pick      <<<64,   256, 0, stream>>>(z, ew, out, out);
    vq_write_loss<<<1024, 256, 0, stream>>>(z, ew, out, part);
    vq_loss      <<<1,    256, 0, stream>>>(part, out);
}

// Round 10
// 45.465 us; speedup vs baseline: 2.6126x; 2.6126x over previous
//
#include <hip/hip_runtime.h>

#define NROWS 65536
#define DIM   64
#define NE    512

// d_out is FLOAT32: [ z_q (4194304) | indices-as-float (65536) | loss (1) ]
// Scratch inside z_q region (consumed by vq_mfma/vq_rescan, then fully
// overwritten by vq_write_loss):
//   bytes [0,131072)      : preSplit — 512 rows x 256B: (-2e)_hi XOR-swizzled
//                           in [0,128), (-2e)_lo mirrored at +128
//   bytes [131072,139264) : preY     — 512 x 16B: (ynorm_hi, ynorm_lo, 0...)
//   floats [34816,35328)  : ynorm f32 (np-pairwise, exact)
//   float  [1048576]      : flag counter (as uint)
//   floats [1048577,...)  : flagged-row list (as uint)
#define PREY_BYTES 131072
#define YN_FLT     34816
#define CTR_FLT    1048576

typedef __attribute__((ext_vector_type(8)))  short bf16x8;
typedef __attribute__((ext_vector_type(16))) float f32x16;

static __device__ __forceinline__ unsigned short bf16rne(float x) {
    unsigned int u = __float_as_uint(x);
    u += 0x7FFFu + ((u >> 16) & 1u);            // RNE (finite inputs only)
    return (unsigned short)(u >> 16);
}
static __device__ __forceinline__ float bf16tof(unsigned short h) {
    return __uint_as_float(((unsigned int)h) << 16);
}

// K0: one-time codebook prep (512 rows, 2 blocks) + zero flag counter.
__global__ __launch_bounds__(256) void vq_prep(
    const float* __restrict__ ew, float* out)
{
    const int r = blockIdx.x * 256 + threadIdx.x;     // 0..511
    if (r == 0) ((unsigned int*)(out + CTR_FLT))[0] = 0u;
    float a[64];
    const float4* src = (const float4*)(ew + (size_t)r * DIM);
    #pragma unroll
    for (int q = 0; q < 16; ++q) {
        float4 v = src[q];
        a[q*4+0]=v.x; a[q*4+1]=v.y; a[q*4+2]=v.z; a[q*4+3]=v.w;
    }
    // numpy-pairwise ||e||^2 (exact np f32 order)
    float rc[8];
    #pragma unroll
    for (int j = 0; j < 8; ++j) rc[j] = __fmul_rn(a[j], a[j]);
    #pragma unroll
    for (int i = 8; i < 64; i += 8)
        #pragma unroll
        for (int j = 0; j < 8; ++j)
            rc[j] = __fadd_rn(rc[j], __fmul_rn(a[i+j], a[i+j]));
    float Y = __fadd_rn(__fadd_rn(__fadd_rn(rc[0],rc[1]),__fadd_rn(rc[2],rc[3])),
                        __fadd_rn(__fadd_rn(rc[4],rc[5]),__fadd_rn(rc[6],rc[7])));
    out[YN_FLT + r] = Y;
    unsigned short ynh = bf16rne(Y);
    unsigned short ynl = bf16rne(Y - bf16tof(ynh));
    bf16x8 py = {};
    py[0] = (short)ynh; py[1] = (short)ynl;
    *(bf16x8*)((char*)out + PREY_BYTES + r*16) = py;
    const int sw = (r & 7) << 4;
    char* base = (char*)out + (size_t)r * 256;
    #pragma unroll
    for (int c = 0; c < 8; ++c) {
        bf16x8 h, l;
        #pragma unroll
        for (int j = 0; j < 8; ++j) {
            float x = -2.0f * a[c*8+j];
            unsigned short hb = bf16rne(x);
            h[j] = (short)hb;
            l[j] = (short)bf16rne(x - bf16tof(hb));
        }
        int off = (c*16) ^ sw;
        *(bf16x8*)(base + off) = h;
        *(bf16x8*)(base + off + 128) = l;
    }
}

// K1: MFMA ranking (proven core) + fused pick: writes f32 winner per row,
// appends near-tie rows (per-row threshold 2*ulp(X)+2e-6) to compacted list.
__global__ __launch_bounds__(256) void vq_mfma(
    const float* __restrict__ z, float* out)
{
    __shared__ __align__(16) char lds[65536 + 8192];
    const float* pre = out;
    const int tid  = threadIdx.x;
    const int lane = tid & 63;
    const int w    = tid >> 6;
    const int hh   = lane >> 5;
    const int l31  = lane & 31;
    const int zrow = blockIdx.x * 128 + w * 32 + l31;

    bf16x8 zh[4], zl[4];
    float xacc = 0.f;                       // f32 sum-sq of this lane's half-row
    {
        const float* zp = z + (size_t)zrow * DIM + hh * 8;
        #pragma unroll
        for (int kt = 0; kt < 4; ++kt) {
            float4 p0 = *(const float4*)(zp + kt*16);
            float4 p1 = *(const float4*)(zp + kt*16 + 4);
            float a[8] = {p0.x,p0.y,p0.z,p0.w,p1.x,p1.y,p1.z,p1.w};
            bf16x8 hv, lv;
            #pragma unroll
            for (int j = 0; j < 8; ++j) {
                unsigned short hb = bf16rne(a[j]);
                hv[j] = (short)hb;
                lv[j] = (short)bf16rne(a[j] - bf16tof(hb));
                xacc  = fmaf(a[j], a[j], xacc);
            }
            zh[kt] = hv; zl[kt] = lv;
        }
    }

    #pragma unroll
    for (int i = 0; i < 2; ++i)
        *(float4*)(lds + 65536 + (tid + 256*i)*16) =
            *(const float4*)((const char*)pre + PREY_BYTES + (tid + 256*i)*16);

    const bf16x8 zero8 = {};
    bf16x8 bones = {};
    if (hh == 0) { bones[0] = (short)0x3F80; bones[1] = (short)0x3F80; }

    float d1 = 3.4e38f, d2 = 3.4e38f;
    int   i1 = 0;

    for (int h = 0; h < 2; ++h) {
        __syncthreads();
        #pragma unroll
        for (int i = 0; i < 16; ++i)
            *(float4*)(lds + tid*16 + i*4096) =
                *(const float4*)((const char*)pre + h*65536 + tid*16 + i*4096);
        __syncthreads();

        for (int t = 0; t < 8; ++t) {
            const int   arow  = t*32 + l31;
            const char* abase = lds + arow*256;
            const int   sw    = (arow & 7) << 4;
            f32x16 acc;
            #pragma unroll
            for (int g = 0; g < 16; ++g) acc[g] = 0.f;
            #pragma unroll
            for (int kt = 0; kt < 4; ++kt) {
                const int kb = (kt*32 + hh*16) ^ sw;
                bf16x8 ah = *(const bf16x8*)(abase + kb);
                bf16x8 al = *(const bf16x8*)(abase + kb + 128);
                acc = __builtin_amdgcn_mfma_f32_32x32x16_bf16(ah, zh[kt], acc, 0,0,0);
                acc = __builtin_amdgcn_mfma_f32_32x32x16_bf16(ah, zl[kt], acc, 0,0,0);
                acc = __builtin_amdgcn_mfma_f32_32x32x16_bf16(al, zh[kt], acc, 0,0,0);
            }
            bf16x8 ay = *(const bf16x8*)(lds + 65536 + (h*256 + t*32 + l31)*16);
            if (hh) ay = zero8;
            acc = __builtin_amdgcn_mfma_f32_32x32x16_bf16(ay, bones, acc, 0,0,0);

            const int ebase = h*256 + t*32 + 4*hh;
            #pragma unroll
            for (int g = 0; g < 16; ++g) {
                float d = acc[g];
                int   e = ebase + (g & 3) + 8*(g >> 2);
                d2 = fminf(fmaxf(d, d1), d2);      // second-smallest value
                bool bt = d < d1;
                i1 = bt ? e : i1;
                d1 = fminf(d, d1);
            }
        }
    }

    // merge half-lane pools; winner (tie -> lower index); per-row flag
    float od1 = __shfl_xor(d1, 32, 64);
    int   oi1 = __shfl_xor(i1, 32, 64);
    float od2 = __shfl_xor(d2, 32, 64);
    bool  oth = (od1 < d1) || (od1 == d1 && oi1 < i1);
    int   wi  = oth ? oi1 : i1;
    float s1  = fminf(d1, od1);
    float s2  = fminf(fmaxf(d1, od1), fminf(d2, od2));
    // per-row threshold: 2*ulp(X + Y) + margin; X from f32 sum (order-free)
    float Xs  = xacc + __shfl_xor(xacc, 32, 64) + 1e-3f;
    float ue  = __uint_as_float(__float_as_uint(Xs) & 0x7F800000u) * 1.1920929e-7f;
    bool  flag = (s2 - s1) < (2.0f * ue + 2e-6f);

    if (hh == 0) {
        out[(size_t)NROWS * DIM + zrow] = (float)wi;
        if (flag) {
            unsigned int* ctr = (unsigned int*)(out + CTR_FLT);
            unsigned int pos = atomicAdd(ctr, 1u);
            ctr[1 + pos] = (unsigned int)zrow;
        }
    }
}

// K2: one block per flagged row (grid-strided over compacted list).
// Exact np-f32 argmin over all 512 embeds: d = fl32(fl32(X+Y) - 2*f64dot).
__global__ __launch_bounds__(256) void vq_rescan(
    const float* __restrict__ z, const float* __restrict__ ew, float* out)
{
    __shared__ float zs[64];
    __shared__ float rd[4];
    __shared__ int   ri[4];
    const int tid  = threadIdx.x;
    const int lane = tid & 63;
    const int w    = tid >> 6;
    const unsigned int* ctr = (const unsigned int*)(out + CTR_FLT);
    const unsigned int count = ctr[0];

    for (unsigned int it = blockIdx.x; it < count; it += gridDim.x) {
        const int row = (int)ctr[1 + it];
        __syncthreads();                   // zs reusable (prior iter done)
        if (tid < 16)
            *(float4*)(zs + tid*4) = *(const float4*)(z + (size_t)row * DIM + tid*4);
        __syncthreads();

        // np-pairwise ||z||^2 (exact np order), computed per thread
        float rc[8];
        #pragma unroll
        for (int j = 0; j < 8; ++j) rc[j] = __fmul_rn(zs[j], zs[j]);
        #pragma unroll
        for (int i = 8; i < 64; i += 8)
            #pragma unroll
            for (int j = 0; j < 8; ++j)
                rc[j] = __fadd_rn(rc[j], __fmul_rn(zs[i+j], zs[i+j]));
        float xn = __fadd_rn(__fadd_rn(__fadd_rn(rc[0],rc[1]),__fadd_rn(rc[2],rc[3])),
                             __fadd_rn(__fadd_rn(rc[4],rc[5]),__fadd_rn(rc[6],rc[7])));

        // two embeds per thread, 4 independent f64 chains each
        float bd = 3.4e38f; int bi = NE;
        #pragma unroll
        for (int half = 0; half < 2; ++half) {
            int e = tid + half * 256;
            const float* ep = ew + (size_t)e * DIM;
            double m0 = 0.0, m1 = 0.0, m2 = 0.0, m3 = 0.0;
            #pragma unroll
            for (int q = 0; q < 16; ++q) {
                float4 ev = *(const float4*)(ep + q*4);
                m0 = fma((double)zs[q*4+0], (double)ev.x, m0);
                m1 = fma((double)zs[q*4+1], (double)ev.y, m1);
                m2 = fma((double)zs[q*4+2], (double)ev.z, m2);
                m3 = fma((double)zs[q*4+3], (double)ev.w, m3);
            }
            double m = (m0 + m1) + (m2 + m3);
            float W = __fadd_rn(xn, out[YN_FLT + e]);   // yn scratch still live
            float d = __fadd_rn(W, -(2.0f * (float)m));
            if (d < bd || (d == bd && e < bi)) { bd = d; bi = e; }
        }
        #pragma unroll
        for (int off = 32; off >= 1; off >>= 1) {
            float od = __shfl_xor(bd, off, 64);
            int   oi = __shfl_xor(bi, off, 64);
            if (od < bd || (od == bd && oi < bi)) { bd = od; bi = oi; }
        }
        if (lane == 0) { rd[w] = bd; ri[w] = bi; }
        __syncthreads();
        if (tid == 0) {
            float fd = rd[0]; int fi = ri[0];
            #pragma unroll
            for (int k = 1; k < 4; ++k)
                if (rd[k] < fd || (rd[k] == fd && ri[k] < fi)) { fd = rd[k]; fi = ri[k]; }
            out[(size_t)NROWS * DIM + row] = (float)fi;
        }
    }
}

// K3: gather e_win, write z_q (coalesced), accumulate f32 loss partials.
// Overwrites all scratch in the z_q region.
__global__ __launch_bounds__(256) void vq_write_loss(
    const float* __restrict__ z, const float* __restrict__ ew,
    float* out, float* __restrict__ part)
{
    __shared__ int ridx[64];
    __shared__ float wsum[4];
    const int tid = threadIdx.x;
    const int R0  = blockIdx.x * 64;
    if (tid < 64)
        ridx[tid] = ((int)out[(size_t)NROWS * DIM + R0 + tid]) & (NE - 1);
    __syncthreads();
    float s = 0.f;
    #pragma unroll
    for (int i = 0; i < 4; ++i) {
        int f4  = tid + 256 * i;
        int row = f4 >> 4;
        int c4  = f4 & 15;
        float4 v  = *(const float4*)(ew + (size_t)ridx[row] * DIM + c4 * 4);
        float4 zz = *(const float4*)(z + (size_t)R0 * DIM + (size_t)f4 * 4);
        *(float4*)(out + (size_t)R0 * DIM + (size_t)f4 * 4) = v;
        float dx = zz.x - v.x, dy = zz.y - v.y, dz2 = zz.z - v.z, dw = zz.w - v.w;
        s = fmaf(dx, dx, s); s = fmaf(dy, dy, s);
        s = fmaf(dz2, dz2, s); s = fmaf(dw, dw, s);
    }
    #pragma unroll
    for (int off = 32; off >= 1; off >>= 1) s += __shfl_xor(s, off, 64);
    if ((tid & 63) == 0) wsum[tid >> 6] = s;
    __syncthreads();
    if (tid == 0) part[blockIdx.x] = wsum[0]+wsum[1]+wsum[2]+wsum[3];
}

// K4: f64 sum of 1024 per-block partials -> loss slot.
__global__ __launch_bounds__(256) void vq_loss(
    const float* __restrict__ part, float* out)
{
    __shared__ double ws[4];
    int tid = threadIdx.x;
    double s = 0.0;
    #pragma unroll
    for (int i = 0; i < 4; ++i) s += (double)part[tid + 256*i];
    #pragma unroll
    for (int off = 32; off >= 1; off >>= 1) s += __shfl_xor(s, off, 64);
    if ((tid & 63) == 0) ws[tid >> 6] = s;
    __syncthreads();
    if (tid == 0)
        out[(size_t)NROWS*DIM + NROWS] =
            (float)(0.25 * (ws[0]+ws[1]+ws[2]+ws[3]) / (double)((size_t)NROWS*DIM));
}

extern "C" void kernel_launch(void* const* d_in, const int* in_sizes, int n_in,
                              void* d_out, int out_size, void* d_ws, size_t ws_size,
                              hipStream_t stream) {
    const float* z  = (const float*)d_in[0];
    const float* ew = (const float*)d_in[1];
    float* out  = (float*)d_out;
    float* part = (float*)d_ws;   // 1024 floats, fully overwritten every call
    vq_prep      <<<2,    256, 0, stream>>>(ew, out);
    vq_mfma      <<<512,  256, 0, stream>>>(z, out);
    vq_rescan    <<<128,  256, 0, stream>>>(z, ew, out);
    vq_write_loss<<<1024, 256, 0, stream>>>(z, ew, out, part);
    vq_loss      <<<1,    256, 0, stream>>>(part, out);
}